// Round 6
// baseline (250.453 us; speedup 1.0000x reference)
//
#include <hip/hip_runtime.h>
#include <stdint.h>

typedef __attribute__((ext_vector_type(8))) short bf16x8;
typedef __attribute__((ext_vector_type(4))) short bf16x4;
typedef __attribute__((ext_vector_type(4))) float f32x4;

#define RT_STRIDE 40   // shorts per c-row: 32 n-slots + 8 pad = 80 B (16B-aligned)
#define A_STRIDE  40   // shorts per k-row of a-tile
#define VB_STRIDE 68   // fp32 reduction-row stride
#define WAVE_SHORTS (64*RT_STRIDE + 32*A_STRIDE)   // 3840 shorts = 7680 B / wave

static __device__ __forceinline__ unsigned short f2bf(float f) {
    union { float f; unsigned int i; } x; x.f = f;
    unsigned int i = x.i;
    return (unsigned short)((i + 0x7FFFu + ((i >> 16) & 1u)) >> 16);  // RNE
}

static __device__ __forceinline__ bf16x8 cvt8(float4 a, float4 b) {
    bf16x8 r;
    r[0] = (short)f2bf(a.x); r[1] = (short)f2bf(a.y);
    r[2] = (short)f2bf(a.z); r[3] = (short)f2bf(a.w);
    r[4] = (short)f2bf(b.x); r[5] = (short)f2bf(b.y);
    r[6] = (short)f2bf(b.z); r[7] = (short)f2bf(b.w);
    return r;
}

// VALU-pipe 16-lane sum via DPP row rotations (row_ror:8,4,2,1)
static __device__ __forceinline__ float row_sum16(float x) {
    union fi { float f; int i; };
    fi a, b; a.f = x;
    b.i = __builtin_amdgcn_mov_dpp(a.i, 0x128, 0xf, 0xf, false); a.f += b.f;
    b.i = __builtin_amdgcn_mov_dpp(a.i, 0x124, 0xf, 0xf, false); a.f += b.f;
    b.i = __builtin_amdgcn_mov_dpp(a.i, 0x122, 0xf, 0xf, false); a.f += b.f;
    b.i = __builtin_amdgcn_mov_dpp(a.i, 0x121, 0xf, 0xf, false); a.f += b.f;
    return a.f;
}

// Grid: 1024 = 256 m x 4 n-quarters; block 256 thr = 4 waves; 4 blocks/CU
// co-resident (16 waves/CU). Per wave: 128 rows as 8 stages of 16.
// R is read ONCE (registers); GEMM2's B comes from a swizzled transposed
// LDS tile written from those registers:
//   store  r[n][c] -> rt[c*40 + (n ^ (quad_w<<3))]   (quad_w = (c>>3)&3)
//   load   B-frag (ct): b128 @ rt[(ct*16+l15)*40 + 8*(quad ^ v)],
//          v = (2*ct + (l15>>3)) & 3   -> 8 contiguous shorts, k-order intact.
// No cross-wave sync in the main loop; partial v combined via atomicAdd.
__global__ __launch_bounds__(256, 4)
void netvlad_fused(const float* __restrict__ R,
                   const float* __restrict__ W,
                   const float* __restrict__ bias,
                   const float* __restrict__ cent,
                   float* __restrict__ out)
{
    __shared__ short smem[4 * WAVE_SHORTS];   // 30720 B; aliased for reduction
    __shared__ float suma_buf[2][32];

    const int tid  = threadIdx.x;
    const int wave = tid >> 6;
    const int lane = tid & 63;
    const int l15  = lane & 15;
    const int quad = lane >> 4;
    const int m    = blockIdx.x >> 2;
    const int q    = blockIdx.x & 3;

    const float* Rm = R + (size_t)m * (2048 * 64);
    const int row0  = q * 512 + wave * 128;

    short* rt    = smem + wave * WAVE_SHORTS;
    short* a_lds = rt + 64 * RT_STRIDE;

    // W fragments (GEMM1 B-operand)
    bf16x8 wf[2][2];
#pragma unroll
    for (int kt = 0; kt < 2; ++kt)
#pragma unroll
        for (int cc = 0; cc < 2; ++cc) {
            const float* wp = W + (kt*16 + l15)*64 + cc*32 + quad*8;
            wf[kt][cc] = cvt8(*(const float4*)wp, *(const float4*)(wp + 4));
        }
    float bval[2];
    bval[0] = bias[l15];
    bval[1] = bias[16 + l15];

    f32x4 acc[2][4];
#pragma unroll
    for (int kt = 0; kt < 2; ++kt)
#pragma unroll
        for (int ct = 0; ct < 4; ++ct)
            acc[kt][ct] = (f32x4){0.f, 0.f, 0.f, 0.f};
    float suma[2] = {0.f, 0.f};

    // prefetch stage 0 (16 rows): lane holds r[row0+l15][quad*8 .. / +32..]
    float4 cur[4];
    {
        const float* p = Rm + (size_t)(row0 + l15)*64 + quad*8;
        cur[0] = *(const float4*)p;        cur[1] = *(const float4*)(p + 4);
        cur[2] = *(const float4*)(p + 32); cur[3] = *(const float4*)(p + 36);
    }

#pragma unroll
    for (int s = 0; s < 8; ++s) {
        // prefetch next stage (depth-1; 4 KB/wave in flight, 16 waves/CU)
        float4 nxt[4];
        if (s < 7) {
            const float* p = Rm + (size_t)(row0 + (s+1)*16 + l15)*64 + quad*8;
            nxt[0] = *(const float4*)p;        nxt[1] = *(const float4*)(p + 4);
            nxt[2] = *(const float4*)(p + 32); nxt[3] = *(const float4*)(p + 36);
        }

        bf16x8 af0 = cvt8(cur[0], cur[1]);   // c = quad*8 + 0..7
        bf16x8 af1 = cvt8(cur[2], cur[3]);   // c = 32 + quad*8 + 0..7

        // GEMM1: 16 rows x 32 k
        f32x4 d1[2];
#pragma unroll
        for (int kt = 0; kt < 2; ++kt) {
            f32x4 d = (f32x4){0.f, 0.f, 0.f, 0.f};
            d = __builtin_amdgcn_mfma_f32_16x16x32_bf16(af0, wf[kt][0], d, 0, 0, 0);
            d = __builtin_amdgcn_mfma_f32_16x16x32_bf16(af1, wf[kt][1], d, 0, 0, 0);
            d1[kt] = d;
        }

        // softmax over k; row = quad*4 + r, k = kt*16 + l15
        bf16x4 p0, p1;
        float a0s = 0.f, a1s = 0.f;
#pragma unroll
        for (int r = 0; r < 4; ++r) {
            float e0 = __expf(d1[0][r] + bval[0]);
            float e1 = __expf(d1[1][r] + bval[1]);
            float rs = __builtin_amdgcn_rcpf(row_sum16(e0 + e1));
            float a0 = e0 * rs, a1 = e1 * rs;
            a0s += a0; a1s += a1;
            p0[r] = (short)f2bf(a0);
            p1[r] = (short)f2bf(a1);
        }
        suma[0] += a0s; suma[1] += a1s;

        const int nwin = (s & 1) * 16;   // window-local n base for this stage
        *(bf16x4*)(a_lds + l15*A_STRIDE        + nwin + quad*4) = p0;
        *(bf16x4*)(a_lds + (16 + l15)*A_STRIDE + nwin + quad*4) = p1;

        // transposed staging of r: rt[c][n ^ (quad_w<<3)], quad_w = (c>>3)&3 = quad
        {
            const int nsw = (nwin + l15) ^ (quad << 3);
            short* base0 = rt + (quad*8) * RT_STRIDE + nsw;        // cc=0
            short* base1 = rt + (32 + quad*8) * RT_STRIDE + nsw;   // cc=1
#pragma unroll
            for (int e = 0; e < 8; ++e) {
                base0[e * RT_STRIDE] = af0[e];
                base1[e * RT_STRIDE] = af1[e];
            }
        }

        if (s & 1) {   // GEMM2 over the 32-row window (stages s-1, s)
            bf16x8 a2[2];
            a2[0] = *(bf16x8*)(a_lds + l15*A_STRIDE        + quad*8);
            a2[1] = *(bf16x8*)(a_lds + (16 + l15)*A_STRIDE + quad*8);

#pragma unroll
            for (int ct = 0; ct < 4; ++ct) {
                const int v = (2*ct + (l15 >> 3)) & 3;
                bf16x8 b2 = *(bf16x8*)(rt + (ct*16 + l15)*RT_STRIDE + 8*(quad ^ v));
                acc[0][ct] = __builtin_amdgcn_mfma_f32_16x16x32_bf16(a2[0], b2, acc[0][ct], 0, 0, 0);
                acc[1][ct] = __builtin_amdgcn_mfma_f32_16x16x32_bf16(a2[1], b2, acc[1][ct], 0, 0, 0);
            }
        }

        if (s < 7) { cur[0] = nxt[0]; cur[1] = nxt[1]; cur[2] = nxt[2]; cur[3] = nxt[3]; }
    }

    // fold suma over quads (k = l15 / 16+l15 per lane)
#pragma unroll
    for (int kt = 0; kt < 2; ++kt) {
        suma[kt] += __shfl_xor(suma[kt], 16);
        suma[kt] += __shfl_xor(suma[kt], 32);
    }

    // cross-wave tree reduction (4 waves), aliasing smem as fp32 buffers
    float* vbuf = (float*)smem;
    __syncthreads();
    if (wave >= 2) {
        float* dst = vbuf + (wave - 2) * (32 * VB_STRIDE);
#pragma unroll
        for (int kt = 0; kt < 2; ++kt)
#pragma unroll
            for (int ct = 0; ct < 4; ++ct)
#pragma unroll
                for (int r = 0; r < 4; ++r)
                    dst[(kt*16 + quad*4 + r)*VB_STRIDE + ct*16 + l15] = acc[kt][ct][r];
        if (lane < 16) {
            suma_buf[wave - 2][lane]      = suma[0];
            suma_buf[wave - 2][lane + 16] = suma[1];
        }
    }
    __syncthreads();
    if (wave < 2) {
        const float* src = vbuf + wave * (32 * VB_STRIDE);
#pragma unroll
        for (int kt = 0; kt < 2; ++kt)
#pragma unroll
            for (int ct = 0; ct < 4; ++ct)
#pragma unroll
                for (int r = 0; r < 4; ++r)
                    acc[kt][ct][r] += src[(kt*16 + quad*4 + r)*VB_STRIDE + ct*16 + l15];
        suma[0] += suma_buf[wave][l15];
        suma[1] += suma_buf[wave][l15 + 16];
    }
    __syncthreads();
    if (wave == 1) {
#pragma unroll
        for (int kt = 0; kt < 2; ++kt)
#pragma unroll
            for (int ct = 0; ct < 4; ++ct)
#pragma unroll
                for (int r = 0; r < 4; ++r)
                    vbuf[(kt*16 + quad*4 + r)*VB_STRIDE + ct*16 + l15] = acc[kt][ct][r];
        if (lane < 16) {
            suma_buf[0][lane]      = suma[0];
            suma_buf[0][lane + 16] = suma[1];
        }
    }
    __syncthreads();
    if (wave == 0) {
#pragma unroll
        for (int kt = 0; kt < 2; ++kt)
#pragma unroll
            for (int ct = 0; ct < 4; ++ct)
#pragma unroll
                for (int r = 0; r < 4; ++r)
                    acc[kt][ct][r] += vbuf[(kt*16 + quad*4 + r)*VB_STRIDE + ct*16 + l15];
        suma[0] += suma_buf[0][l15];
        suma[1] += suma_buf[0][l15 + 16];

        float* op = out + (size_t)m * (32*64);
#pragma unroll
        for (int kt = 0; kt < 2; ++kt) {
#pragma unroll
            for (int r = 0; r < 4; ++r) {
                const int k = kt*16 + quad*4 + r;
                const float su = __shfl(suma[kt], quad*4 + r);
#pragma unroll
                for (int ct = 0; ct < 4; ++ct) {
                    const int c = ct*16 + l15;
                    atomicAdd(&op[k*64 + c], acc[kt][ct][r] - su * cent[k*64 + c]);
                }
            }
        }
    }
}

extern "C" void kernel_launch(void* const* d_in, const int* in_sizes, int n_in,
                              void* d_out, int out_size, void* d_ws, size_t ws_size,
                              hipStream_t stream) {
    (void)in_sizes; (void)n_in; (void)out_size; (void)d_ws; (void)ws_size;
    const float* R = (const float*)d_in[0];   // R_seq (8,32,2048,64) fp32
    const float* W = (const float*)d_in[1];   // W (32,64) fp32
    const float* b = (const float*)d_in[2];   // b (32,) fp32
    const float* c = (const float*)d_in[3];   // centroids (32,64) fp32
    float* out = (float*)d_out;               // (8,32,32,64) fp32

    hipMemsetAsync(out, 0, (size_t)256 * 32 * 64 * sizeof(float), stream);
    hipLaunchKernelGGL(netvlad_fused, dim3(1024), dim3(256), 0, stream,
                       R, W, b, c, out);
}